// Round 6
// baseline (312.717 us; speedup 1.0000x reference)
//
#include <hip/hip_runtime.h>
#include <hip/hip_bf16.h>

#define N_NODES   100000
#define N_EDGES   1000000
#define N_FEAT    136
#define HIDDEN    64
#define N_CLASSES 2
#define NUM_GRAPHS 512

#define NP_PAD    100352          // 98 * 1024
#define SCAN_BLKS 98

#define E_PAD     1000064

#define K1_4 (N_FEAT / 4)              // 34
#define K2_4 (HIDDEN / 4)              // 16

#define K1PAD 160                      // 136 padded to 5*32, row stride (u16)
#define K2PAD 72                       // 64 + 8 pad to break bank alias

#define NB_E    ((N_EDGES + 255) / 256)      // 3907
#define NB_SC   ((N_EDGES / 4 + 255) / 256)  // 977
#define NB_HIST (NB_E + 3)                   // hist blocks + 3 gbounds blocks = 3910
#define NB_MM   ((N_NODES + 63) / 64)        // 1563
// striped fusion: per 7 blocks, 2 are mm1-role, 5 are hist-role.
#define FUSED_GRID 5474

typedef unsigned short ushort_t;
typedef __attribute__((ext_vector_type(8))) short bf16x8;   // MFMA A/B frag
typedef __attribute__((ext_vector_type(4))) float f32x4;    // MFMA C/D frag
typedef __attribute__((ext_vector_type(4))) int i32x4;
typedef __attribute__((ext_vector_type(4))) unsigned short u16x4;

// fp32 -> bf16 (RTNE), bf16 -> fp32
__device__ __forceinline__ ushort_t f2b(float v) {
    unsigned b = __float_as_uint(v);
    return (ushort_t)((b + 0x7FFF + ((b >> 16) & 1)) >> 16);
}
__device__ __forceinline__ float b2f(ushort_t u) {
    return __uint_as_float(((unsigned)u) << 16);
}
__device__ __forceinline__ unsigned pack2(float a, float b) {
    return (unsigned)f2b(a) | ((unsigned)f2b(b) << 16);
}

// ============ fused: hist (atomic-bound) ∥ mm1 (MFMA-bound) ∥ gbounds =======
// hist: per-dst degree count; the atomicAdd RETURN is the edge's rank within
// its dst segment (rank-based atomic-free scatter downstream).
// mm1: tpb = bf16(x @ W1) UNSCALED. The ~46us 1M-device-atomic stream is a HW
// floor (measured R2/R3/R5); mm1 rides the idle MFMA/VALU pipes beneath it.
__global__ __launch_bounds__(256) void fused_hist_mm1_kernel(
        const int* __restrict__ dst, int* __restrict__ cnt,
        ushort_t* __restrict__ rank,
        const int* __restrict__ batch, int* __restrict__ gstart,
        const float* __restrict__ x, const float* __restrict__ W1,
        ushort_t* __restrict__ tpb) {
    __shared__ ushort_t wtb[64 * K1PAD];   // 20480 B, W1 transposed [n][k] bf16
    int t = threadIdx.x;
    int gq = blockIdx.x / 7, gr = blockIdx.x % 7;

    if (gr >= 2) {                          // ---- hist / gbounds role ----
        int hb = gq * 5 + (gr - 2);
        if (hb >= NB_HIST) return;
        if (hb >= NB_E) {                   // gbounds: lower_bound(batch, g)
            int g = (hb - NB_E) * 256 + t;
            if (g <= NUM_GRAPHS) {
                int lo = 0, hi = N_NODES;
                while (lo < hi) {
                    int mid = (lo + hi) >> 1;
                    if (batch[mid] < g) lo = mid + 1; else hi = mid;
                }
                gstart[g] = lo;
            }
            return;
        }
        int e = hb * 256 + t;
        if (e < N_EDGES) {
            int d = __builtin_nontemporal_load(&dst[e]);
            int r = atomicAdd(&cnt[d], 1);  // rank within segment (deg << 64K)
            __builtin_nontemporal_store((ushort_t)r, &rank[e]);
        }
        return;
    }

    // ---- mm1 role ----
    int mb = gq * 2 + gr;
    if (mb >= NB_MM) return;
    int n0 = mb * 64;
    {
        for (int i = t; i < N_FEAT * HIDDEN; i += 256) {
            int n = i & 63, k = i >> 6;
            wtb[n * K1PAD + k] = f2b(W1[i]);
        }
        for (int i = t; i < 64 * 12; i += 256) {
            int n = i / 12, c = i % 12;
            *(unsigned*)&wtb[n * K1PAD + N_FEAT + 2 * c] = 0;
        }
    }
    __syncthreads();
    int w = t >> 6, lane = t & 63;
    int quad = lane >> 4, l16 = lane & 15;
    int an = n0 + w * 16 + l16; if (an >= N_NODES) an = N_NODES - 1;
    const f32x4* xr = (const f32x4*)(x + (long long)an * N_FEAT);
    f32x4 acc[4] = {{0,0,0,0},{0,0,0,0},{0,0,0,0},{0,0,0,0}};
#pragma unroll
    for (int kc = 0; kc < K1PAD / 32; ++kc) {
        int k0 = kc * 32 + quad * 8;
        bf16x8 a = {0, 0, 0, 0, 0, 0, 0, 0};
        if (k0 < N_FEAT) {                  // chunks are 8-aligned; 136 % 8 == 0
            f32x4 u0 = __builtin_nontemporal_load(&xr[kc * 8 + quad * 2]);
            f32x4 u1 = __builtin_nontemporal_load(&xr[kc * 8 + quad * 2 + 1]);
            union { bf16x8 v; unsigned u[4]; } cv;
            cv.u[0] = pack2(u0.x, u0.y);
            cv.u[1] = pack2(u0.z, u0.w);
            cv.u[2] = pack2(u1.x, u1.y);
            cv.u[3] = pack2(u1.z, u1.w);
            a = cv.v;
        }
#pragma unroll
        for (int nt = 0; nt < 4; ++nt) {
            bf16x8 b = *(const bf16x8*)&wtb[(nt * 16 + l16) * K1PAD + kc * 32 + quad * 8];
            acc[nt] = __builtin_amdgcn_mfma_f32_16x16x32_bf16(a, b, acc[nt], 0, 0, 0);
        }
    }
#pragma unroll
    for (int r = 0; r < 4; ++r) {
        int nl = w * 16 + quad * 4 + r;
        int node = n0 + nl;
        if (node < N_NODES) {
#pragma unroll
            for (int nt = 0; nt < 4; ++nt)
                tpb[node * 64 + nt * 16 + l16] = f2b(acc[nt][r]);   // unscaled
        }
    }
}

__global__ __launch_bounds__(256) void scan1_kernel(const int* __restrict__ cnt,
                                                    int* __restrict__ row_ptr,
                                                    int* __restrict__ partials) {
    __shared__ int sd[256];
    int b = blockIdx.x, t = threadIdx.x;
    int i0 = b * 1024 + t * 4;
    int c0 = (i0 + 0 < N_NODES) ? cnt[i0 + 0] : 0;
    int c1 = (i0 + 1 < N_NODES) ? cnt[i0 + 1] : 0;
    int c2 = (i0 + 2 < N_NODES) ? cnt[i0 + 2] : 0;
    int c3 = (i0 + 3 < N_NODES) ? cnt[i0 + 3] : 0;
    int tsum = c0 + c1 + c2 + c3;
    sd[t] = tsum;
    __syncthreads();
    for (int off = 1; off < 256; off <<= 1) {
        int v = (t >= off) ? sd[t - off] : 0;
        __syncthreads();
        sd[t] += v;
        __syncthreads();
    }
    int excl = sd[t] - tsum;
    row_ptr[i0 + 0] = excl;
    row_ptr[i0 + 1] = excl + c0;
    row_ptr[i0 + 2] = excl + c0 + c1;
    row_ptr[i0 + 3] = excl + c0 + c1 + c2;
    if (t == 255) partials[b] = sd[255];
}

__global__ __launch_bounds__(128) void scan2_kernel(int* __restrict__ partials) {
    __shared__ int sd[128];
    int t = threadIdx.x;
    int v = (t < SCAN_BLKS) ? partials[t] : 0;
    sd[t] = v;
    __syncthreads();
    for (int off = 1; off < 128; off <<= 1) {
        int u = (t >= off) ? sd[t - off] : 0;
        __syncthreads();
        sd[t] += u;
        __syncthreads();
    }
    partials[t] = sd[t] - v;
}

// scan3: finalize row_ptr + dinv. (dst_sorted expansion REMOVED — node-parallel
// aggregation needs only row_ptr + csr_src.)
__global__ __launch_bounds__(256) void scan3_kernel(int* __restrict__ row_ptr,
                                                    const int* __restrict__ cnt,
                                                    const int* __restrict__ partials,
                                                    float* __restrict__ dinv) {
    int i = blockIdx.x * 256 + threadIdx.x;
    if (i < N_NODES) {
        int v = row_ptr[i] + partials[i >> 10];
        row_ptr[i] = v;
        dinv[i] = rsqrtf((float)(cnt[i] + 1));        // +1 self-loop
    }
    if (i == N_NODES) row_ptr[N_NODES] = N_EDGES;
}

// atomic-free scatter: pos = row_ptr[d] + rank[e]. One coalesced pass.
__global__ __launch_bounds__(256) void scatter_kernel(const int* __restrict__ src,
                                                      const int* __restrict__ dst,
                                                      const ushort_t* __restrict__ rank,
                                                      const int* __restrict__ row_ptr,
                                                      int* __restrict__ csr_src) {
    int e0 = (blockIdx.x * 256 + threadIdx.x) * 4;
    if (e0 >= N_EDGES) return;                        // N_EDGES % 4 == 0
    i32x4 s4 = __builtin_nontemporal_load((const i32x4*)&src[e0]);
    i32x4 d4 = __builtin_nontemporal_load((const i32x4*)&dst[e0]);
    u16x4 r4 = *(const u16x4*)&rank[e0];
    int p0 = row_ptr[d4.x] + (int)r4.x;
    int p1 = row_ptr[d4.y] + (int)r4.y;
    int p2 = row_ptr[d4.z] + (int)r4.z;
    int p3 = row_ptr[d4.w] + (int)r4.w;
    csr_src[p0] = s4.x;
    csr_src[p1] = s4.y;
    csr_src[p2] = s4.z;
    csr_src[p3] = s4.w;
}

// ====== mm2agg: node-parallel layer-1 aggregation + epilogue + mm2 ==========
// Per wave: 16 dst nodes, lane = feature. CSR gather (coalesced 128B rows),
// register accumulate — NO atomics, NO agg buffer, NO dst_sorted.
// h1 tile -> LDS -> MFMA W2 -> tpb2 = (h1@W2)*dinv (scaled), NOT in-place.
__global__ __launch_bounds__(256) void mm2agg_kernel(
        const int* __restrict__ row_ptr, const int* __restrict__ csr_src,
        const ushort_t* __restrict__ tpb,     // layer-1 t1, unscaled
        const float* __restrict__ dinv,
        const float* __restrict__ W2, const float* __restrict__ bias,
        ushort_t* __restrict__ tpb2) {
    __shared__ ushort_t hsb[64 * K2PAD];   // 9216 B, h1 tile
    __shared__ ushort_t wtb[64 * K2PAD];   // 9216 B, W2 transposed [n][k]
    int t = threadIdx.x;
    int n0 = blockIdx.x * 64;
    for (int i = t; i < HIDDEN * HIDDEN; i += 256) {
        int n = i & 63, k = i >> 6;
        wtb[n * K2PAD + k] = f2b(W2[i]);
    }
    for (int i = t; i < 64 * 4; i += 256) {
        int n = i / 4, c = i % 4;
        *(unsigned*)&wtb[n * K2PAD + HIDDEN + 2 * c] = 0;
        *(unsigned*)&hsb[n * K2PAD + HIDDEN + 2 * c] = 0;
    }
    int w = t >> 6, lane = t & 63;
    float bl = bias[lane];
    // ---- gather-aggregate: wave w owns nodes n0+w*16 .. +15 ----
    for (int nl = 0; nl < 16; ++nl) {
        int n_raw = n0 + w * 16 + nl;
        int n = (n_raw < N_NODES) ? n_raw : N_NODES - 1;
        int r0 = row_ptr[n], r1 = row_ptr[n + 1];
        float a = 0.0f;
        for (int base = r0; base < r1; base += 64) {
            int cnt = r1 - base; if (cnt > 64) cnt = 64;
            int sv = csr_src[base + (lane < cnt ? lane : cnt - 1)];
            int j = 0;
            for (; j + 1 < cnt; j += 2) {       // 2-deep: overlap row loads
                int s0 = __builtin_amdgcn_readlane(sv, j);
                int s1 = __builtin_amdgcn_readlane(sv, j + 1);
                float v0 = dinv[s0] * b2f(tpb[(size_t)s0 * 64 + lane]);
                float v1 = dinv[s1] * b2f(tpb[(size_t)s1 * 64 + lane]);
                a += v0 + v1;
            }
            if (j < cnt) {
                int s0 = __builtin_amdgcn_readlane(sv, j);
                a += dinv[s0] * b2f(tpb[(size_t)s0 * 64 + lane]);
            }
        }
        float dn = dinv[n];
        // h1 = relu(dn*(sum + dn*t1_self) + b1)
        float h = fmaxf(fmaf(fmaf(dn, b2f(tpb[(size_t)n * 64 + lane]), a), dn, bl), 0.f);
        hsb[(w * 16 + nl) * K2PAD + lane] = f2b(h);
    }
    __syncthreads();
    // ---- MFMA: t2 = h1 @ W2 ----
    int quad = lane >> 4, l16 = lane & 15;
    f32x4 acc[4] = {{0,0,0,0},{0,0,0,0},{0,0,0,0},{0,0,0,0}};
#pragma unroll
    for (int kc = 0; kc < 2; ++kc) {
        bf16x8 a = *(const bf16x8*)&hsb[(w * 16 + l16) * K2PAD + kc * 32 + quad * 8];
#pragma unroll
        for (int nt = 0; nt < 4; ++nt) {
            bf16x8 b = *(const bf16x8*)&wtb[(nt * 16 + l16) * K2PAD + kc * 32 + quad * 8];
            acc[nt] = __builtin_amdgcn_mfma_f32_16x16x32_bf16(a, b, acc[nt], 0, 0, 0);
        }
    }
#pragma unroll
    for (int r = 0; r < 4; ++r) {
        int nl = w * 16 + quad * 4 + r;
        int node = n0 + nl;
        if (node < N_NODES) {
            float di = dinv[node];
#pragma unroll
            for (int nt = 0; nt < 4; ++nt)
                tpb2[node * 64 + nt * 16 + l16] = f2b(acc[nt][r] * di);  // scaled
        }
    }
}

// ====== agg2: node-parallel layer-2 aggregation + epilogue -> h2 bf16 =======
// tpb2 already carries dinv[src]: a = sum(tpb2_s); h2 = relu(dn*(a+tpb2_n)+b2)
__global__ __launch_bounds__(256) void agg2_kernel(
        const int* __restrict__ row_ptr, const int* __restrict__ csr_src,
        const ushort_t* __restrict__ tpb2, const float* __restrict__ dinv,
        const float* __restrict__ bias, ushort_t* __restrict__ h2) {
    int t = threadIdx.x;
    int n0 = blockIdx.x * 64;
    int w = t >> 6, lane = t & 63;
    float bl = bias[lane];
    for (int nl = 0; nl < 16; ++nl) {
        int n = n0 + w * 16 + nl;
        if (n >= N_NODES) break;            // wave-uniform
        int r0 = row_ptr[n], r1 = row_ptr[n + 1];
        float a = 0.0f;
        for (int base = r0; base < r1; base += 64) {
            int cnt = r1 - base; if (cnt > 64) cnt = 64;
            int sv = csr_src[base + (lane < cnt ? lane : cnt - 1)];
            int j = 0;
            for (; j + 1 < cnt; j += 2) {
                int s0 = __builtin_amdgcn_readlane(sv, j);
                int s1 = __builtin_amdgcn_readlane(sv, j + 1);
                float v0 = b2f(tpb2[(size_t)s0 * 64 + lane]);
                float v1 = b2f(tpb2[(size_t)s1 * 64 + lane]);
                a += v0 + v1;
            }
            if (j < cnt) {
                int s0 = __builtin_amdgcn_readlane(sv, j);
                a += b2f(tpb2[(size_t)s0 * 64 + lane]);
            }
        }
        float dn = dinv[n];
        float h = fmaxf(fmaf(a + b2f(tpb2[(size_t)n * 64 + lane]), dn, bl), 0.f);
        h2[(size_t)n * 64 + lane] = f2b(h);
    }
}

// ---- pool + head: one BLOCK per graph; h2 is final (epilogue pre-applied) --
__global__ __launch_bounds__(256) void gpool_kernel(const ushort_t* __restrict__ h2,
                                                    const int* __restrict__ gstart,
                                                    const float* __restrict__ Wout,
                                                    const float* __restrict__ bout,
                                                    float* __restrict__ out) {
    __shared__ float red[4][64];
    int lane = threadIdx.x & 63;
    int w = threadIdx.x >> 6;
    int g = blockIdx.x;                      // 512 blocks
    int s = gstart[g], e = gstart[g + 1];
    float acc = 0.0f;
    for (int n = s + w; n < e; n += 4)
        acc += b2f(h2[(size_t)n * 64 + lane]);
    red[w][lane] = acc;
    __syncthreads();
    if (threadIdx.x < 64) {
        float tot = red[0][lane] + red[1][lane] + red[2][lane] + red[3][lane];
        float p = tot / fmaxf((float)(e - s), 1.0f);      // pooled mean
        float c0 = p * Wout[lane * N_CLASSES + 0];
        float c1 = p * Wout[lane * N_CLASSES + 1];
#pragma unroll
        for (int off = 32; off > 0; off >>= 1) {
            c0 += __shfl_down(c0, off);
            c1 += __shfl_down(c1, off);
        }
        if (lane == 0) {
            out[g * N_CLASSES + 0] = c0 + bout[0];
            out[g * N_CLASSES + 1] = c1 + bout[1];
        }
    }
}

extern "C" void kernel_launch(void* const* d_in, const int* in_sizes, int n_in,
                              void* d_out, int out_size, void* d_ws, size_t ws_size,
                              hipStream_t stream) {
    const float* x     = (const float*)d_in[0];
    const int*   ei    = (const int*)d_in[1];
    const int*   batch = (const int*)d_in[2];
    const float* W1    = (const float*)d_in[3];
    const float* b1    = (const float*)d_in[4];
    const float* W2    = (const float*)d_in[5];
    const float* b2    = (const float*)d_in[6];
    const float* Wout  = (const float*)d_in[7];
    const float* bout  = (const float*)d_in[8];
    float* out = (float*)d_out;

    const int* src = ei;
    const int* dst = ei + N_EDGES;

    // -------- workspace layout (~31 MB) --------
    char* p = (char*)d_ws;
    int*      row_ptr   = (int*)p;      p += (NP_PAD + 256) * sizeof(int);
    int*      cnt       = (int*)p;      p += NP_PAD * sizeof(int);   // histogram
    int*      partials  = (int*)p;      p += 256 * sizeof(int);
    int*      gstart    = (int*)p;      p += (NUM_GRAPHS + 64) * sizeof(int);
    int*      csr_src   = (int*)p;      p += (size_t)E_PAD * sizeof(int);
    float*    dinv      = (float*)p;    p += NP_PAD * sizeof(float);
    ushort_t* tpb       = (ushort_t*)p; p += (size_t)N_NODES * HIDDEN * sizeof(ushort_t);
    ushort_t* tpb2      = (ushort_t*)p; p += (size_t)N_NODES * HIDDEN * sizeof(ushort_t);
    // rank16 (2 MB) live only hist->scatter; tpb2 first written by mm2agg
    // (after scatter) -> alias. h2 (12.8 MB) aliases tpb (dead after mm2agg).
    ushort_t* rank16    = (ushort_t*)tpb2;
    ushort_t* h2        = tpb;

    // -------- CSR build: hist ∥ mm1 ∥ gbounds, scans, rank-scatter --------
    hipMemsetAsync(cnt, 0, NP_PAD * sizeof(int), stream);
    fused_hist_mm1_kernel<<<FUSED_GRID, 256, 0, stream>>>(dst, cnt, rank16,
                                                          batch, gstart,
                                                          x, W1, tpb);
    scan1_kernel<<<SCAN_BLKS, 256, 0, stream>>>(cnt, row_ptr, partials);
    scan2_kernel<<<1, 128, 0, stream>>>(partials);
    scan3_kernel<<<NP_PAD / 256 + 1, 256, 0, stream>>>(row_ptr, cnt, partials, dinv);
    scatter_kernel<<<NB_SC, 256, 0, stream>>>(src, dst, rank16, row_ptr, csr_src);

    // -------- layer1 agg + epilogue + mm2 (node-parallel, atomic-free) ------
    mm2agg_kernel<<<NB_MM, 256, 0, stream>>>(row_ptr, csr_src, tpb, dinv,
                                             W2, b1, tpb2);
    // -------- layer2 agg + epilogue --------
    agg2_kernel<<<NB_MM, 256, 0, stream>>>(row_ptr, csr_src, tpb2, dinv, b2, h2);

    // -------- pool + head --------
    gpool_kernel<<<NUM_GRAPHS, 256, 0, stream>>>(h2, gstart, Wout, bout, out);
}